// Round 3
// baseline (545.127 us; speedup 1.0000x reference)
//
#include <hip/hip_runtime.h>
#include <math.h>

static constexpr int B = 32, C = 256, HW = 4096, CS = 16;
static constexpr int BHW = B * HW;                 // 131072
static constexpr size_t IMG = (size_t)B * CS * HW; // 2,097,152 floats per branch buffer

// ---------- workspace layout (floats) ----------
static constexpr size_t OFF_S     = 0;        // 8 ops x 512 (b*16+k) per-(b,c) sums
static constexpr size_t OFF_SQ    = 4096;     // 8 ops x 512 sumsq
static constexpr size_t OFF_U     = 8192;     // u3sum[16],u3sq[16],u5sum[16],u5sq[16]
static constexpr size_t ACC_FLOATS= 8256;     // zeroed each launch
static constexpr size_t OFF_MX    = 8256;
static constexpr size_t OFF_AV    = OFF_MX + 8192;
static constexpr size_t OFF_NUM   = OFF_AV + 8192;
static constexpr size_t OFF_SLIST = OFF_NUM + 8192;
static constexpr size_t OFF_Y     = OFF_SLIST + 256;   // B*128
static constexpr size_t OFF_ACO   = OFF_Y + 4096;      // B*16*8
static constexpr size_t OFF_BIAS  = OFF_ACO + 4096;    // B*16
static constexpr size_t OFF_INT   = OFF_BIAS + 512;    // idx[16], selmap[256] as ints
static constexpr size_t OFF_XT    = 42112;
static constexpr size_t OFF_R     = OFF_XT + IMG;      // 6 branch buffers

__device__ inline float wave_sum(float v) {
  v += __shfl_down(v, 32); v += __shfl_down(v, 16); v += __shfl_down(v, 8);
  v += __shfl_down(v, 4);  v += __shfl_down(v, 2);  v += __shfl_down(v, 1);
  return v;
}
__device__ inline float wave_max(float v) {
  v = fmaxf(v, __shfl_down(v, 32)); v = fmaxf(v, __shfl_down(v, 16));
  v = fmaxf(v, __shfl_down(v, 8));  v = fmaxf(v, __shfl_down(v, 4));
  v = fmaxf(v, __shfl_down(v, 2));  v = fmaxf(v, __shfl_down(v, 1));
  return v;
}

// ---- K1: per-(b,c) max and mean over HxW ----
__global__ __launch_bounds__(256) void k_stats(const float4* __restrict__ x,
                                               float* __restrict__ mx, float* __restrict__ av) {
  int bc = blockIdx.x;
  const float4* p = x + (size_t)bc * 1024;
  float mmax = -INFINITY, msum = 0.f;
  for (int i = threadIdx.x; i < 1024; i += 256) {
    float4 v = p[i];
    mmax = fmaxf(mmax, fmaxf(fmaxf(v.x, v.y), fmaxf(v.z, v.w)));
    msum += v.x + v.y + v.z + v.w;
  }
  __shared__ float rs[4], rm[4];
  float s = wave_sum(msum), m = wave_max(mmax);
  int w = threadIdx.x >> 6;
  if ((threadIdx.x & 63) == 0) { rs[w] = s; rm[w] = m; }
  __syncthreads();
  if (threadIdx.x == 0) {
    mx[bc] = fmaxf(fmaxf(rm[0], rm[1]), fmaxf(rm[2], rm[3]));
    av[bc] = (rs[0] + rs[1] + rs[2] + rs[3]) * (1.f / 4096.f);
  }
}

// ---- K2: SE module -> num = sigmoid(se(mx)+se(av)) ----
__global__ __launch_bounds__(128) void k_se(const float* __restrict__ mx, const float* __restrict__ av,
                                            const float* __restrict__ w1, const float* __restrict__ w2,
                                            float* __restrict__ num) {
  int b = blockIdx.x, t = threadIdx.x;
  __shared__ float zs[2][256], h[2][128];
  for (int i = t; i < 256; i += 128) { zs[0][i] = mx[b * 256 + i]; zs[1][i] = av[b * 256 + i]; }
  __syncthreads();
  {
    const float* wr = w1 + (size_t)t * 256;
    float am = 0.f, aa = 0.f;
    for (int i = 0; i < 256; i++) { float w = wr[i]; am = fmaf(w, zs[0][i], am); aa = fmaf(w, zs[1][i], aa); }
    h[0][t] = fmaxf(am, 0.f); h[1][t] = fmaxf(aa, 0.f);
  }
  __syncthreads();
  for (int c = t; c < 256; c += 128) {
    const float* wr = w2 + (size_t)c * 128;
    float sm = 0.f, sa = 0.f;
    for (int j = 0; j < 128; j++) { float w = wr[j]; sm = fmaf(w, h[0][j], sm); sa = fmaf(w, h[1][j], sa); }
    float s = sm + sa;
    num[b * 256 + c] = 1.f / (1.f + expf(-s));
  }
}

// ---- K3: top-16, rank-based parallel (lax.top_k order: desc, ties->lowest idx) ----
__global__ __launch_bounds__(256) void k_select(const float* __restrict__ num,
                                                int* __restrict__ idx, int* __restrict__ selmap) {
  __shared__ float s[256];
  int t = threadIdx.x;
  float acc = 0.f;
  for (int b = 0; b < B; b++) acc += num[b * 256 + t];
  s[t] = acc; selmap[t] = -1;
  __syncthreads();
  float v = s[t];
  int rank = 0;
  for (int c = 0; c < 256; c++) {
    float o = s[c];
    rank += (o > v) || (o == v && c < t);
  }
  if (rank < 16) { idx[rank] = t; selmap[t] = rank; }
}

// ---- K4: xt = x[:,idx]*num ; also per-(b,k) sum (identity-branch mean) ----
__global__ __launch_bounds__(256) void k_gather(const float* __restrict__ x, const float* __restrict__ num,
                                                const int* __restrict__ idx, float* __restrict__ xt,
                                                float* __restrict__ Sdst) {
  int bk = blockIdx.x, b = bk >> 4, k = bk & 15;
  int c = idx[k];
  float sc = num[b * 256 + c];
  const float4* src = (const float4*)(x + ((size_t)b * 256 + c) * HW);
  float4* dst = (float4*)(xt + (size_t)bk * HW);
  float sum = 0.f;
  for (int i = threadIdx.x; i < 1024; i += 256) {
    float4 v = src[i];
    v.x *= sc; v.y *= sc; v.z *= sc; v.w *= sc;
    dst[i] = v; sum += v.x + v.y + v.z + v.w;
  }
  __shared__ float rs[4];
  float s = wave_sum(sum);
  if ((threadIdx.x & 63) == 0) rs[threadIdx.x >> 6] = s;
  __syncthreads();
  if (threadIdx.x == 0) Sdst[bk] = rs[0] + rs[1] + rs[2] + rs[3];
}

// =================== fused branch kernels ===================
// Block = (op, b, 4-row tile). Loader stages 16ch x (4+2P) rows x 64 cols in LDS
// (zero rows for OOB). Thread = one output pixel: computes dw for all 16 channels
// into registers (taps conflict-free: consecutive lanes -> consecutive banks;
// weights wave-uniform -> SGPR), then 16x16 pw matvec, writes out + atomicAdd stats.

// MODE 0: relu(in); MODE 1: relu((in-m)*rs) with per-channel stats from ustats
template<int KK, int DIL, int MODE>
__device__ __forceinline__ void dwpw_tile(
    const float* __restrict__ in, const float* __restrict__ dwW, const float* __restrict__ pwW,
    float* __restrict__ out, float* __restrict__ Ss, float* __restrict__ Qs, int statPerB,
    const float* __restrict__ ustats, int b, int rt,
    float* lt, float* redS, float* redQ, float* msh, float* rssh)
{
  constexpr int P = (KK / 2) * DIL;
  constexpr int ROWS = 4 + 2 * P;
  const int t = threadIdx.x;
  if (MODE == 1) {
    if (t < 16) {
      float mu = ustats[t] * (1.f / (float)BHW);
      float var = ustats[16 + t] * (1.f / (float)BHW) - mu * mu;
      msh[t] = mu; rssh[t] = rsqrtf(var + 1e-5f);
    }
    __syncthreads();
  }
  const int y0 = rt * 4;
  for (int idx = t; idx < 16 * ROWS * 64; idx += 256) {
    int c = idx & 63; int rc = idx >> 6; int rr = rc % ROWS; int ch = rc / ROWS;
    int y = y0 - P + rr;
    float v = 0.f;
    if (y >= 0 && y < 64) {
      v = in[(size_t)(b * 16 + ch) * HW + y * 64 + c];
      if (MODE == 1) v = (v - msh[ch]) * rssh[ch];
      v = fmaxf(v, 0.f);
    }
    lt[idx] = v;
  }
  __syncthreads();
  // per-pixel dw for all 16 channels -> registers
  const int r = t >> 6, c0 = t & 63;
  float sv[16];
#pragma unroll
  for (int ch = 0; ch < 16; ch++) {
    const float* tch = lt + ch * ROWS * 64;
    const float* wch = dwW + ch * KK * KK;
    float acc = 0.f;
#pragma unroll
    for (int a = 0; a < KK; a++) {
#pragma unroll
      for (int q = 0; q < KK; q++) {
        int cc = c0 - P + q * DIL;
        float tv = (cc >= 0 && cc < 64) ? tch[(r + a * DIL) * 64 + cc] : 0.f;
        acc = fmaf(wch[a * KK + q], tv, acc);
      }
    }
    sv[ch] = acc;
  }
  // pw 16x16 + stats
  const int wv = t >> 6, lane = t & 63;
#pragma unroll
  for (int cc = 0; cc < 16; cc++) {
    float acc = 0.f;
#pragma unroll
    for (int i = 0; i < 16; i++) acc = fmaf(pwW[cc * 16 + i], sv[i], acc);
    out[(size_t)(b * 16 + cc) * HW + rt * 256 + t] = acc;
    float s = wave_sum(acc), q = wave_sum(acc * acc);
    if (lane == 0) { redS[cc * 4 + wv] = s; redQ[cc * 4 + wv] = q; }
  }
  __syncthreads();
  if (t < 16) {
    float s = redS[t * 4] + redS[t * 4 + 1] + redS[t * 4 + 2] + redS[t * 4 + 3];
    float q = redQ[t * 4] + redQ[t * 4 + 1] + redQ[t * 4 + 2] + redQ[t * 4 + 3];
    int sl = statPerB ? b * 16 + t : t;
    atomicAdd(&Ss[sl], s); atomicAdd(&Qs[sl], q);
  }
}

__device__ __forceinline__ void pools_tile(
    const float* __restrict__ in, float* __restrict__ outMax, float* __restrict__ outAvg,
    float* __restrict__ Ss1, float* __restrict__ Qs1, float* __restrict__ Ss2, float* __restrict__ Qs2,
    int b, int rt, float* lt, float* redA, float* redB, float* redC, float* redD)
{
  const int t = threadIdx.x;
  const int y0 = rt * 4;
  for (int idx = t; idx < 16 * 6 * 64; idx += 256) {
    int c = idx & 63; int rc = idx >> 6; int rr = rc % 6; int ch = rc / 6;
    int y = y0 - 1 + rr;
    float v = 0.f;
    if (y >= 0 && y < 64) v = in[(size_t)(b * 16 + ch) * HW + y * 64 + c];
    lt[idx] = v;
  }
  __syncthreads();
  const int r = t >> 6, c = t & 63;
  const int y = y0 + r;
  const int ry0 = max(y - 1, 0) - y0 + 1, ry1 = min(y + 1, 63) - y0 + 1;
  const int cx0 = max(c - 1, 0), cx1 = min(c + 1, 63);
  const float inv = 1.f / (float)((ry1 - ry0 + 1) * (cx1 - cx0 + 1));
  const int wv = t >> 6, lane = t & 63;
#pragma unroll
  for (int ch = 0; ch < 16; ch++) {
    const float* tch = lt + ch * 6 * 64;
    float mx = -INFINITY, sm = 0.f;
    for (int rr = ry0; rr <= ry1; rr++)
      for (int xx = cx0; xx <= cx1; xx++) { float v = tch[rr * 64 + xx]; mx = fmaxf(mx, v); sm += v; }
    float av = sm * inv;
    size_t o = (size_t)(b * 16 + ch) * HW + y * 64 + c;
    outMax[o] = mx; outAvg[o] = av;
    float s1 = wave_sum(mx), q1 = wave_sum(mx * mx);
    float s2 = wave_sum(av), q2 = wave_sum(av * av);
    if (lane == 0) { redA[ch * 4 + wv] = s1; redB[ch * 4 + wv] = q1; redC[ch * 4 + wv] = s2; redD[ch * 4 + wv] = q2; }
  }
  __syncthreads();
  if (t < 16) {
    float s1 = redA[t * 4] + redA[t * 4 + 1] + redA[t * 4 + 2] + redA[t * 4 + 3];
    float q1 = redB[t * 4] + redB[t * 4 + 1] + redB[t * 4 + 2] + redB[t * 4 + 3];
    float s2 = redC[t * 4] + redC[t * 4 + 1] + redC[t * 4 + 2] + redC[t * 4 + 3];
    float q2 = redD[t * 4] + redD[t * 4 + 1] + redD[t * 4 + 2] + redD[t * 4 + 3];
    atomicAdd(&Ss1[b * 16 + t], s1); atomicAdd(&Qs1[b * 16 + t], q1);
    atomicAdd(&Ss2[b * 16 + t], s2); atomicAdd(&Qs2[b * 16 + t], q2);
  }
}

// KA: pools + dil3 + dil5 + sep3-stage1 + sep5-stage1  (5 ops x 512 tiles)
__global__ __launch_bounds__(256) void k_branch1(
    const float* __restrict__ xt,
    const float* __restrict__ d3dw, const float* __restrict__ d3pw,
    const float* __restrict__ d5dw, const float* __restrict__ d5pw,
    const float* __restrict__ s3dw1, const float* __restrict__ s3pw1,
    const float* __restrict__ s5dw1, const float* __restrict__ s5pw1,
    float* __restrict__ R, float* __restrict__ t3, float* __restrict__ t5,
    float* __restrict__ S, float* __restrict__ SQ, float* __restrict__ U)
{
  __shared__ float lt[16 * 12 * 64];
  __shared__ float redA[64], redB[64], redC[64], redD[64];
  __shared__ float msh[16], rssh[16];
  int blk = blockIdx.x;
  int op = blk % 5, rem = blk / 5;
  int b = rem >> 4, rt = rem & 15;
  switch (op) {
    case 0: pools_tile(xt, R, R + IMG, S + 512, SQ + 512, S + 1024, SQ + 1024, b, rt, lt, redA, redB, redC, redD); break;
    case 1: dwpw_tile<3, 2, 0>(xt, d3dw, d3pw, R + 4 * IMG, S + 6 * 512, SQ + 6 * 512, 1, nullptr, b, rt, lt, redA, redB, msh, rssh); break;
    case 2: dwpw_tile<5, 2, 0>(xt, d5dw, d5pw, R + 5 * IMG, S + 7 * 512, SQ + 7 * 512, 1, nullptr, b, rt, lt, redA, redB, msh, rssh); break;
    case 3: dwpw_tile<3, 1, 0>(xt, s3dw1, s3pw1, t3, U + 0, U + 16, 0, nullptr, b, rt, lt, redA, redB, msh, rssh); break;
    case 4: dwpw_tile<5, 1, 0>(xt, s5dw1, s5pw1, t5, U + 32, U + 48, 0, nullptr, b, rt, lt, redA, redB, msh, rssh); break;
  }
}

// KB: sep3-stage2 + sep5-stage2 (bn from U, then dw2+pw2)
__global__ __launch_bounds__(256) void k_branch2(
    const float* __restrict__ t3, const float* __restrict__ t5,
    const float* __restrict__ s3dw2, const float* __restrict__ s3pw2,
    const float* __restrict__ s5dw2, const float* __restrict__ s5pw2,
    float* __restrict__ R, float* __restrict__ S, float* __restrict__ SQ, float* __restrict__ U)
{
  __shared__ float lt[16 * 8 * 64];
  __shared__ float redA[64], redB[64];
  __shared__ float msh[16], rssh[16];
  int blk = blockIdx.x;
  int op = blk & 1, rem = blk >> 1;
  int b = rem >> 4, rt = rem & 15;
  if (op == 0)
    dwpw_tile<3, 1, 1>(t3, s3dw2, s3pw2, R + 2 * IMG, S + 4 * 512, SQ + 4 * 512, 1, U + 0, b, rt, lt, redA, redB, msh, rssh);
  else
    dwpw_tile<5, 1, 1>(t5, s5dw2, s5pw2, R + 3 * IMG, S + 5 * 512, SQ + 5 * 512, 1, U + 32, b, rt, lt, redA, redB, msh, rssh);
}

// ---- attention MLP + per-(b,k) accumulation coefficients ----
__global__ __launch_bounds__(128) void k_att(const float* __restrict__ S, const float* __restrict__ SQ,
                                             const float* __restrict__ w1, const float* __restrict__ w2,
                                             float* __restrict__ y, float* __restrict__ aco,
                                             float* __restrict__ bia) {
  int b = blockIdx.x, t = threadIdx.x;
  __shared__ float ym[128], h[16], msh[8][16], rssh[8][16], ysh[128];
  int op = t >> 4, k = t & 15;
  bool isbn = (op == 1 || op == 2 || op >= 4);
  float m = 0.f, rsc = 0.f;
  {
    float ss = 0.f, qq = 0.f;
    for (int bb = 0; bb < B; bb++) { ss += S[op * 512 + bb * 16 + k]; qq += SQ[op * 512 + bb * 16 + k]; }
    if (isbn) {
      m = ss * (1.f / (float)BHW);
      float var = qq * (1.f / (float)BHW) - m * m;
      rsc = rsqrtf(var + 1e-5f);
    }
  }
  msh[op][k] = m; rssh[op][k] = rsc;
  float sm = S[op * 512 + b * 16 + k] * (1.f / 4096.f);
  float yme = (op == 0) ? 0.f : ((op == 3) ? sm : (sm - m) * rsc);
  ym[t] = yme;
  __syncthreads();
  if (t < 16) {
    const float* wr = w1 + (size_t)t * 128;
    float acc = 0.f;
    for (int c = 0; c < 128; c++) acc = fmaf(wr[c], ym[c], acc);
    h[t] = fmaxf(acc, 0.f);
  }
  __syncthreads();
  {
    const float* wr = w2 + (size_t)t * 16;
    float acc = 0.f;
    for (int j = 0; j < 16; j++) acc = fmaf(wr[j], h[j], acc);
    float yy = 1.f / (1.f + expf(-acc));
    ysh[t] = yy; y[b * 128 + t] = yy;
  }
  __syncthreads();
  if (t < 16) {
    float bias = 0.f;
    for (int o2 = 1; o2 < 8; o2++) {
      float yv = ysh[o2 * 16 + t];
      float a;
      if (o2 == 3) a = yv;
      else { a = yv * rssh[o2][t]; bias -= yv * rssh[o2][t] * msh[o2][t]; }
      aco[(b * 16 + t) * 8 + o2] = a;
    }
    bia[b * 16 + t] = bias;
  }
}

// ---- final fused write (+ op_attention in the extra block) ----
__global__ __launch_bounds__(256) void k_final(const float* __restrict__ x, const float* __restrict__ num,
                                               const int* __restrict__ selmap, const float* __restrict__ xt,
                                               const float* __restrict__ rbuf, const float* __restrict__ aco,
                                               const float* __restrict__ bia, const float* __restrict__ ybuf,
                                               float* __restrict__ out, float* __restrict__ out8) {
  __shared__ float sh[256];
  int bc = blockIdx.x;
  if (bc == B * C) {
    int t = threadIdx.x, op = t >> 5, lane = t & 31;
    float acc = 0.f;
    for (int i = lane; i < 512; i += 32) { int bb = i >> 4, kk = i & 15; acc += ybuf[bb * 128 + op * 16 + kk]; }
    sh[t] = acc;
    __syncthreads();
    if (lane == 0) {
      float s = 0.f;
      for (int i = 0; i < 32; i++) s += sh[op * 32 + i];
      out8[op] = s;
    }
    return;
  }
  int b = bc >> 8;
  int k = selmap[bc & 255];
  const float4* xs = (const float4*)(x + (size_t)bc * HW);
  float4* od = (float4*)(out + (size_t)bc * HW);
  if (k < 0) {
    float sc = 1.f + num[bc];
    for (int i = threadIdx.x; i < 1024; i += 256) {
      float4 v = xs[i];
      v.x *= sc; v.y *= sc; v.z *= sc; v.w *= sc;
      od[i] = v;
    }
  } else {
    int bk = b * 16 + k;
    const float4* xtp = (const float4*)(xt + (size_t)bk * HW);
    const float4* r0 = (const float4*)(rbuf + ((size_t)0 * 512 + bk) * HW);
    const float4* r1 = (const float4*)(rbuf + ((size_t)1 * 512 + bk) * HW);
    const float4* r2 = (const float4*)(rbuf + ((size_t)2 * 512 + bk) * HW);
    const float4* r3 = (const float4*)(rbuf + ((size_t)3 * 512 + bk) * HW);
    const float4* r4 = (const float4*)(rbuf + ((size_t)4 * 512 + bk) * HW);
    const float4* r5 = (const float4*)(rbuf + ((size_t)5 * 512 + bk) * HW);
    float a1 = aco[bk * 8 + 1], a2 = aco[bk * 8 + 2], a3 = aco[bk * 8 + 3], a4 = aco[bk * 8 + 4];
    float a5 = aco[bk * 8 + 5], a6 = aco[bk * 8 + 6], a7 = aco[bk * 8 + 7];
    float bias = bia[bk];
    for (int i = threadIdx.x; i < 1024; i += 256) {
      float4 xv = xs[i], tv = xtp[i];
      float4 v0 = r0[i], v1 = r1[i], v2 = r2[i], v3 = r3[i], v4 = r4[i], v5 = r5[i];
      float4 o;
      o.x = xv.x + bias + a1 * v0.x + a2 * v1.x + a3 * tv.x + a4 * v2.x + a5 * v3.x + a6 * v4.x + a7 * v5.x;
      o.y = xv.y + bias + a1 * v0.y + a2 * v1.y + a3 * tv.y + a4 * v2.y + a5 * v3.y + a6 * v4.y + a7 * v5.y;
      o.z = xv.z + bias + a1 * v0.z + a2 * v1.z + a3 * tv.z + a4 * v2.z + a5 * v3.z + a6 * v4.z + a7 * v5.z;
      o.w = xv.w + bias + a1 * v0.w + a2 * v1.w + a3 * tv.w + a4 * v2.w + a5 * v3.w + a6 * v4.w + a7 * v5.w;
      od[i] = o;
    }
  }
}

extern "C" void kernel_launch(void* const* d_in, const int* in_sizes, int n_in,
                              void* d_out, int out_size, void* d_ws, size_t ws_size,
                              hipStream_t stream) {
  const float* x      = (const float*)d_in[0];
  const float* ca_w1  = (const float*)d_in[1];
  const float* ca_w2  = (const float*)d_in[2];
  const float* s3_dw1 = (const float*)d_in[3];
  const float* s3_pw1 = (const float*)d_in[4];
  const float* s3_dw2 = (const float*)d_in[5];
  const float* s3_pw2 = (const float*)d_in[6];
  const float* s5_dw1 = (const float*)d_in[7];
  const float* s5_pw1 = (const float*)d_in[8];
  const float* s5_dw2 = (const float*)d_in[9];
  const float* s5_pw2 = (const float*)d_in[10];
  const float* d3_dw  = (const float*)d_in[11];
  const float* d3_pw  = (const float*)d_in[12];
  const float* d5_dw  = (const float*)d_in[13];
  const float* d5_pw  = (const float*)d_in[14];
  const float* at_w1  = (const float*)d_in[15];
  const float* at_w2  = (const float*)d_in[16];

  float* ws = (float*)d_ws;
  float* S = ws + OFF_S;  float* SQ = ws + OFF_SQ;  float* U = ws + OFF_U;
  float* mx = ws + OFF_MX; float* av = ws + OFF_AV; float* num = ws + OFF_NUM;
  float* ybuf = ws + OFF_Y; float* aco = ws + OFF_ACO; float* bia = ws + OFF_BIAS;
  int* ib = (int*)(ws + OFF_INT);
  int* idx = ib; int* selmap = ib + 16;
  float* xt = ws + OFF_XT; float* R = ws + OFF_R;

  float* outf = (float*)d_out;
  float* t3 = outf;        // scratch inside d_out, dead before k_final
  float* t5 = outf + IMG;
  float* out8 = outf + (size_t)B * C * HW;

  hipMemsetAsync(ws, 0, ACC_FLOATS * sizeof(float), stream);

  k_stats<<<B * C, 256, 0, stream>>>((const float4*)x, mx, av);
  k_se<<<B, 128, 0, stream>>>(mx, av, ca_w1, ca_w2, num);
  k_select<<<1, 256, 0, stream>>>(num, idx, selmap);
  k_gather<<<B * CS, 256, 0, stream>>>(x, num, idx, xt, S + 3 * 512);

  k_branch1<<<5 * 512, 256, 0, stream>>>(xt, d3_dw, d3_pw, d5_dw, d5_pw,
                                         s3_dw1, s3_pw1, s5_dw1, s5_pw1,
                                         R, t3, t5, S, SQ, U);
  k_branch2<<<2 * 512, 256, 0, stream>>>(t3, t5, s3_dw2, s3_pw2, s5_dw2, s5_pw2,
                                         R, S, SQ, U);

  k_att<<<B, 128, 0, stream>>>(S, SQ, at_w1, at_w2, ybuf, aco, bia);
  k_final<<<B * C + 1, 256, 0, stream>>>(x, num, selmap, xt, R, aco, bia, ybuf, outf, out8);
}

// Round 4
// 213.552 us; speedup vs baseline: 2.5527x; 2.5527x over previous
//
#include <hip/hip_runtime.h>
#include <math.h>

static constexpr int B = 32, C = 256, HW = 4096, CS = 16;
static constexpr int BHW = B * HW;                 // 131072
static constexpr size_t IMG = (size_t)B * CS * HW; // 2,097,152 floats per branch buffer

// ---------- workspace layout (floats) ----------
static constexpr size_t OFF_S     = 0;        // 8 ops x 512 (b*16+k) per-(b,c) sums
static constexpr size_t OFF_SQ    = 4096;     // 8 ops x 512 sumsq
static constexpr size_t OFF_U     = 8192;     // u3sum[16],u3sq[16],u5sum[16],u5sq[16]
static constexpr size_t ACC_FLOATS= 8256;     // zeroed in k_select
static constexpr size_t OFF_MX    = 8256;
static constexpr size_t OFF_AV    = OFF_MX + 8192;
static constexpr size_t OFF_NUM   = OFF_AV + 8192;
static constexpr size_t OFF_Y     = OFF_NUM + 8192;    // B*128
static constexpr size_t OFF_ACO   = OFF_Y + 4096;      // B*16*8
static constexpr size_t OFF_BIAS  = OFF_ACO + 4096;    // B*16
static constexpr size_t OFF_INT   = OFF_BIAS + 512;    // idx[16], selmap[256] as ints
static constexpr size_t OFF_R     = 42112;             // 6 branch buffers (16B aligned)

__device__ inline float wave_sum(float v) {
  v += __shfl_down(v, 32); v += __shfl_down(v, 16); v += __shfl_down(v, 8);
  v += __shfl_down(v, 4);  v += __shfl_down(v, 2);  v += __shfl_down(v, 1);
  return v;
}
__device__ inline float wave_max(float v) {
  v = fmaxf(v, __shfl_down(v, 32)); v = fmaxf(v, __shfl_down(v, 16));
  v = fmaxf(v, __shfl_down(v, 8));  v = fmaxf(v, __shfl_down(v, 4));
  v = fmaxf(v, __shfl_down(v, 2));  v = fmaxf(v, __shfl_down(v, 1));
  return v;
}

// ---- K1: per-(b,c) max and mean over HxW ----
__global__ __launch_bounds__(256) void k_stats(const float4* __restrict__ x,
                                               float* __restrict__ mx, float* __restrict__ av) {
  int bc = blockIdx.x;
  const float4* p = x + (size_t)bc * 1024;
  float mmax = -INFINITY, msum = 0.f;
  for (int i = threadIdx.x; i < 1024; i += 256) {
    float4 v = p[i];
    mmax = fmaxf(mmax, fmaxf(fmaxf(v.x, v.y), fmaxf(v.z, v.w)));
    msum += v.x + v.y + v.z + v.w;
  }
  __shared__ float rs[4], rm[4];
  float s = wave_sum(msum), m = wave_max(mmax);
  int w = threadIdx.x >> 6;
  if ((threadIdx.x & 63) == 0) { rs[w] = s; rm[w] = m; }
  __syncthreads();
  if (threadIdx.x == 0) {
    mx[bc] = fmaxf(fmaxf(rm[0], rm[1]), fmaxf(rm[2], rm[3]));
    av[bc] = (rs[0] + rs[1] + rs[2] + rs[3]) * (1.f / 4096.f);
  }
}

// ---- K2: SE module -> num = sigmoid(se(mx)+se(av)) ----
__global__ __launch_bounds__(128) void k_se(const float* __restrict__ mx, const float* __restrict__ av,
                                            const float* __restrict__ w1, const float* __restrict__ w2,
                                            float* __restrict__ num) {
  int b = blockIdx.x, t = threadIdx.x;
  __shared__ float zs[2][256], h[2][128];
  for (int i = t; i < 256; i += 128) { zs[0][i] = mx[b * 256 + i]; zs[1][i] = av[b * 256 + i]; }
  __syncthreads();
  {
    const float* wr = w1 + (size_t)t * 256;
    float am = 0.f, aa = 0.f;
    for (int i = 0; i < 256; i++) { float w = wr[i]; am = fmaf(w, zs[0][i], am); aa = fmaf(w, zs[1][i], aa); }
    h[0][t] = fmaxf(am, 0.f); h[1][t] = fmaxf(aa, 0.f);
  }
  __syncthreads();
  for (int c = t; c < 256; c += 128) {
    const float* wr = w2 + (size_t)c * 128;
    float sm = 0.f, sa = 0.f;
    for (int j = 0; j < 128; j++) { float w = wr[j]; sm = fmaf(w, h[0][j], sm); sa = fmaf(w, h[1][j], sa); }
    float s = sm + sa;
    num[b * 256 + c] = 1.f / (1.f + expf(-s));
  }
}

// ---- K3: zero accumulators + top-16 rank-parallel (lax.top_k order) ----
__global__ __launch_bounds__(256) void k_select(const float* __restrict__ num,
                                                int* __restrict__ idx, int* __restrict__ selmap,
                                                float* __restrict__ accbase) {
  __shared__ float s[256];
  int t = threadIdx.x;
  for (int i = t; i < (int)ACC_FLOATS; i += 256) accbase[i] = 0.f;
  float acc = 0.f;
  for (int b = 0; b < B; b++) acc += num[b * 256 + t];
  s[t] = acc; selmap[t] = -1;
  __syncthreads();
  float v = s[t];
  int rank = 0;
  for (int c = 0; c < 256; c++) {
    float o = s[c];
    rank += (o > v) || (o == v && c < t);
  }
  if (rank < 16) { idx[rank] = t; selmap[t] = rank; }
}

// ---- full-image depthwise conv on one channel; input staged with gate*relu (opt. bn) ----
template<int KK, int DIL, int BN>
__device__ __forceinline__ void dw_full(const float* __restrict__ src, float sc,
                                        const float* __restrict__ w, float* __restrict__ dst,
                                        float* lt, float mu, float rs) {
  constexpr int P = (KK / 2) * DIL, TW = 64 + 2 * P;
  float wr[KK * KK];
#pragma unroll
  for (int i = 0; i < KK * KK; i++) wr[i] = w[i];
  for (int i = threadIdx.x; i < TW * TW; i += 256) {
    int ty = i / TW, tx = i - ty * TW;
    int y = ty - P, xx = tx - P;
    float v = 0.f;
    if ((unsigned)y < 64u && (unsigned)xx < 64u) {
      v = src[y * 64 + xx] * sc;
      if (BN) v = (v - mu) * rs;
      v = fmaxf(v, 0.f);
    }
    lt[i] = v;
  }
  __syncthreads();
  for (int i = threadIdx.x; i < HW; i += 256) {
    int y = i >> 6, xx = i & 63;
    const float* t0 = lt + y * TW + xx;
    float acc = 0.f;
#pragma unroll
    for (int a = 0; a < KK; a++)
#pragma unroll
      for (int q = 0; q < KK; q++)
        acc = fmaf(wr[a * KK + q], t0[a * DIL * TW + q * DIL], acc);
    dst[i] = acc;
  }
}

// ---- pools on one channel (raw gated input), direct stats (ops 1,2) + identity sum (op 3) ----
__device__ __forceinline__ void pools_full(const float* __restrict__ src, float sc,
                                           float* __restrict__ dmax, float* __restrict__ davg,
                                           float* __restrict__ S, float* __restrict__ SQ,
                                           int bk, float* lt, float* red) {
  for (int i = threadIdx.x; i < HW; i += 256) lt[i] = src[i] * sc;
  __syncthreads();
  float s1 = 0.f, q1 = 0.f, s2 = 0.f, q2 = 0.f, s3 = 0.f;
  for (int i = threadIdx.x; i < HW; i += 256) {
    int y = i >> 6, xx = i & 63;
    int y0 = max(y - 1, 0), y1 = min(y + 1, 63), x0 = max(xx - 1, 0), x1 = min(xx + 1, 63);
    float mx = -INFINITY, sm = 0.f;
    for (int yy = y0; yy <= y1; yy++)
      for (int cx = x0; cx <= x1; cx++) { float v = lt[yy * 64 + cx]; mx = fmaxf(mx, v); sm += v; }
    float av = sm / (float)((y1 - y0 + 1) * (x1 - x0 + 1));
    dmax[i] = mx; davg[i] = av;
    s1 += mx; q1 += mx * mx; s2 += av; q2 += av * av; s3 += lt[i];
  }
  s1 = wave_sum(s1); q1 = wave_sum(q1); s2 = wave_sum(s2); q2 = wave_sum(q2); s3 = wave_sum(s3);
  int w = threadIdx.x >> 6;
  if ((threadIdx.x & 63) == 0) { red[w] = s1; red[4 + w] = q1; red[8 + w] = s2; red[12 + w] = q2; red[16 + w] = s3; }
  __syncthreads();
  if (threadIdx.x == 0) {
    S[512 + bk]  = red[0] + red[1] + red[2] + red[3];
    SQ[512 + bk] = red[4] + red[5] + red[6] + red[7];
    S[1024 + bk] = red[8] + red[9] + red[10] + red[11];
    SQ[1024 + bk]= red[12] + red[13] + red[14] + red[15];
    S[1536 + bk] = red[16] + red[17] + red[18] + red[19];
  }
}

// ---- Phase A: pools + 4 first-stage dw convs, gating applied at stage time ----
__global__ __launch_bounds__(256) void k_branchA(
    const float* __restrict__ x, const float* __restrict__ num, const int* __restrict__ idx,
    const float* __restrict__ d3dw, const float* __restrict__ d5dw,
    const float* __restrict__ s3dw1, const float* __restrict__ s5dw1,
    float* __restrict__ R, float* __restrict__ scr,
    float* __restrict__ S, float* __restrict__ SQ) {
  __shared__ float lt[72 * 72];
  __shared__ float red[20];
  int blk = blockIdx.x;
  int op = blk / 512, bk = blk - op * 512;
  int b = bk >> 4, k = bk & 15;
  int c = idx[k];
  float sc = num[b * 256 + c];
  const float* src = x + ((size_t)b * 256 + c) * HW;
  size_t o = (size_t)bk * HW;
  switch (op) {
    case 0: pools_full(src, sc, R + o, R + IMG + o, S, SQ, bk, lt, red); break;
    case 1: dw_full<3, 2, 0>(src, sc, d3dw + k * 9,  scr + 0 * IMG + o, lt, 0.f, 0.f); break;
    case 2: dw_full<5, 2, 0>(src, sc, d5dw + k * 25, scr + 1 * IMG + o, lt, 0.f, 0.f); break;
    case 3: dw_full<3, 1, 0>(src, sc, s3dw1 + k * 9,  scr + 2 * IMG + o, lt, 0.f, 0.f); break;
    case 4: dw_full<5, 1, 0>(src, sc, s5dw1 + k * 25, scr + 3 * IMG + o, lt, 0.f, 0.f); break;
  }
}

// ---- pointwise 16x16: registers only; stats via atomics ----
__device__ __forceinline__ void pw_tile(const float* __restrict__ in, const float* __restrict__ w16,
                                        float* __restrict__ out, float* __restrict__ sacc,
                                        float* __restrict__ qacc, int perB, int b, int tile,
                                        float* wsh, float* redS, float* redQ) {
  int t = threadIdx.x;
  wsh[t] = w16[t];
  size_t base = (size_t)b * 16 * HW + tile * 256;
  float sv[16];
#pragma unroll
  for (int i = 0; i < 16; i++) sv[i] = in[base + (size_t)i * HW + t];
  __syncthreads();
  int wv = t >> 6, lane = t & 63;
#pragma unroll
  for (int cc = 0; cc < 16; cc++) {
    float acc = 0.f;
#pragma unroll
    for (int i = 0; i < 16; i++) acc = fmaf(wsh[cc * 16 + i], sv[i], acc);
    out[base + (size_t)cc * HW + t] = acc;
    float s = wave_sum(acc), q = wave_sum(acc * acc);
    if (lane == 0) { redS[cc * 4 + wv] = s; redQ[cc * 4 + wv] = q; }
  }
  __syncthreads();
  if (t < 16) {
    float s = redS[t * 4] + redS[t * 4 + 1] + redS[t * 4 + 2] + redS[t * 4 + 3];
    float q = redQ[t * 4] + redQ[t * 4 + 1] + redQ[t * 4 + 2] + redQ[t * 4 + 3];
    int sl = perB ? b * 16 + t : t;
    atomicAdd(&sacc[sl], s); atomicAdd(&qacc[sl], q);
  }
}

// ---- Phase B: pw for dil3, dil5 (->R + stats), sep3a, sep5a (->t3/t5 + U stats) ----
__global__ __launch_bounds__(256) void k_branchB(
    const float* __restrict__ scr,
    const float* __restrict__ d3pw, const float* __restrict__ d5pw,
    const float* __restrict__ s3pw1, const float* __restrict__ s5pw1,
    float* __restrict__ R, float* __restrict__ t3, float* __restrict__ t5,
    float* __restrict__ S, float* __restrict__ SQ, float* __restrict__ U) {
  __shared__ float wsh[256], redS[64], redQ[64];
  int blk = blockIdx.x;
  int op = blk >> 9, rem = blk & 511;
  int b = rem >> 4, tile = rem & 15;
  switch (op) {
    case 0: pw_tile(scr + 0 * IMG, d3pw,  R + 4 * IMG, S + 6 * 512, SQ + 6 * 512, 1, b, tile, wsh, redS, redQ); break;
    case 1: pw_tile(scr + 1 * IMG, d5pw,  R + 5 * IMG, S + 7 * 512, SQ + 7 * 512, 1, b, tile, wsh, redS, redQ); break;
    case 2: pw_tile(scr + 2 * IMG, s3pw1, t3, U + 0,  U + 16, 0, b, tile, wsh, redS, redQ); break;
    case 3: pw_tile(scr + 3 * IMG, s5pw1, t5, U + 32, U + 48, 0, b, tile, wsh, redS, redQ); break;
  }
}

// ---- Phase C: second dw convs with lazy-bn from U ----
__global__ __launch_bounds__(256) void k_branchC(
    const float* __restrict__ t3, const float* __restrict__ t5,
    const float* __restrict__ s3dw2, const float* __restrict__ s5dw2,
    float* __restrict__ scr, const float* __restrict__ U) {
  __shared__ float lt[68 * 68];
  int blk = blockIdx.x;
  int op = blk >> 9, bk = blk & 511, k = bk & 15;
  size_t o = (size_t)bk * HW;
  if (op == 0) {
    float mu = U[k] * (1.f / (float)BHW);
    float var = U[16 + k] * (1.f / (float)BHW) - mu * mu;
    float rs = rsqrtf(var + 1e-5f);
    dw_full<3, 1, 1>(t3 + o, 1.f, s3dw2 + k * 9, scr + 0 * IMG + o, lt, mu, rs);
  } else {
    float mu = U[32 + k] * (1.f / (float)BHW);
    float var = U[48 + k] * (1.f / (float)BHW) - mu * mu;
    float rs = rsqrtf(var + 1e-5f);
    dw_full<5, 1, 1>(t5 + o, 1.f, s5dw2 + k * 25, scr + 1 * IMG + o, lt, mu, rs);
  }
}

// ---- Phase D: final pw convs -> R2/R3 + per-(b,c) stats ----
__global__ __launch_bounds__(256) void k_branchD(
    const float* __restrict__ scr,
    const float* __restrict__ s3pw2, const float* __restrict__ s5pw2,
    float* __restrict__ R, float* __restrict__ S, float* __restrict__ SQ) {
  __shared__ float wsh[256], redS[64], redQ[64];
  int blk = blockIdx.x;
  int op = blk >> 9, rem = blk & 511;
  int b = rem >> 4, tile = rem & 15;
  if (op == 0) pw_tile(scr + 0 * IMG, s3pw2, R + 2 * IMG, S + 4 * 512, SQ + 4 * 512, 1, b, tile, wsh, redS, redQ);
  else         pw_tile(scr + 1 * IMG, s5pw2, R + 3 * IMG, S + 5 * 512, SQ + 5 * 512, 1, b, tile, wsh, redS, redQ);
}

// ---- attention MLP + per-(b,k) accumulation coefficients ----
__global__ __launch_bounds__(128) void k_att(const float* __restrict__ S, const float* __restrict__ SQ,
                                             const float* __restrict__ w1, const float* __restrict__ w2,
                                             float* __restrict__ y, float* __restrict__ aco,
                                             float* __restrict__ bia) {
  int b = blockIdx.x, t = threadIdx.x;
  __shared__ float ym[128], h[16], msh[8][16], rssh[8][16], ysh[128];
  int op = t >> 4, k = t & 15;
  bool isbn = (op == 1 || op == 2 || op >= 4);
  float m = 0.f, rsc = 0.f;
  {
    float ss = 0.f, qq = 0.f;
    for (int bb = 0; bb < B; bb++) { ss += S[op * 512 + bb * 16 + k]; qq += SQ[op * 512 + bb * 16 + k]; }
    if (isbn) {
      m = ss * (1.f / (float)BHW);
      float var = qq * (1.f / (float)BHW) - m * m;
      rsc = rsqrtf(var + 1e-5f);
    }
  }
  msh[op][k] = m; rssh[op][k] = rsc;
  float sm = S[op * 512 + b * 16 + k] * (1.f / 4096.f);
  float yme = (op == 0) ? 0.f : ((op == 3) ? sm : (sm - m) * rsc);
  ym[t] = yme;
  __syncthreads();
  if (t < 16) {
    const float* wr = w1 + (size_t)t * 128;
    float acc = 0.f;
    for (int c = 0; c < 128; c++) acc = fmaf(wr[c], ym[c], acc);
    h[t] = fmaxf(acc, 0.f);
  }
  __syncthreads();
  {
    const float* wr = w2 + (size_t)t * 16;
    float acc = 0.f;
    for (int j = 0; j < 16; j++) acc = fmaf(wr[j], h[j], acc);
    float yy = 1.f / (1.f + expf(-acc));
    ysh[t] = yy; y[b * 128 + t] = yy;
  }
  __syncthreads();
  if (t < 16) {
    float bias = 0.f;
    for (int o2 = 1; o2 < 8; o2++) {
      float yv = ysh[o2 * 16 + t];
      float a;
      if (o2 == 3) a = yv;
      else { a = yv * rssh[o2][t]; bias -= yv * rssh[o2][t] * msh[o2][t]; }
      aco[(b * 16 + t) * 8 + o2] = a;
    }
    bia[b * 16 + t] = bias;
  }
}

// ---- final fused write (+ op_attention in the extra block) ----
__global__ __launch_bounds__(256) void k_final(const float* __restrict__ x, const float* __restrict__ num,
                                               const int* __restrict__ selmap, const int* __restrict__ idx,
                                               const float* __restrict__ rbuf, const float* __restrict__ aco,
                                               const float* __restrict__ bia, const float* __restrict__ ybuf,
                                               float* __restrict__ out, float* __restrict__ out8) {
  __shared__ float sh[256];
  int bc = blockIdx.x;
  if (bc == B * C) {
    int t = threadIdx.x, op = t >> 5, lane = t & 31;
    float acc = 0.f;
    for (int i = lane; i < 512; i += 32) { int bb = i >> 4, kk = i & 15; acc += ybuf[bb * 128 + op * 16 + kk]; }
    sh[t] = acc;
    __syncthreads();
    if (lane == 0) {
      float s = 0.f;
      for (int i = 0; i < 32; i++) s += sh[op * 32 + i];
      out8[op] = s;
    }
    return;
  }
  int b = bc >> 8;
  int k = selmap[bc & 255];
  const float4* xs = (const float4*)(x + (size_t)bc * HW);
  float4* od = (float4*)(out + (size_t)bc * HW);
  if (k < 0) {
    float sc = 1.f + num[bc];
    for (int i = threadIdx.x; i < 1024; i += 256) {
      float4 v = xs[i];
      v.x *= sc; v.y *= sc; v.z *= sc; v.w *= sc;
      od[i] = v;
    }
  } else {
    int bk = b * 16 + k;
    int ci = idx[k];
    float scn = num[b * 256 + ci];
    const float4* xtp = (const float4*)(x + ((size_t)b * 256 + ci) * HW);
    const float4* r0 = (const float4*)(rbuf + ((size_t)0 * 512 + bk) * HW);
    const float4* r1 = (const float4*)(rbuf + ((size_t)1 * 512 + bk) * HW);
    const float4* r2 = (const float4*)(rbuf + ((size_t)2 * 512 + bk) * HW);
    const float4* r3 = (const float4*)(rbuf + ((size_t)3 * 512 + bk) * HW);
    const float4* r4 = (const float4*)(rbuf + ((size_t)4 * 512 + bk) * HW);
    const float4* r5 = (const float4*)(rbuf + ((size_t)5 * 512 + bk) * HW);
    float a1 = aco[bk * 8 + 1], a2 = aco[bk * 8 + 2], a3 = aco[bk * 8 + 3] * scn, a4 = aco[bk * 8 + 4];
    float a5 = aco[bk * 8 + 5], a6 = aco[bk * 8 + 6], a7 = aco[bk * 8 + 7];
    float bias = bia[bk];
    for (int i = threadIdx.x; i < 1024; i += 256) {
      float4 xv = xs[i], tv = xtp[i];
      float4 v0 = r0[i], v1 = r1[i], v2 = r2[i], v3 = r3[i], v4 = r4[i], v5 = r5[i];
      float4 o;
      o.x = xv.x + bias + a1 * v0.x + a2 * v1.x + a3 * tv.x + a4 * v2.x + a5 * v3.x + a6 * v4.x + a7 * v5.x;
      o.y = xv.y + bias + a1 * v0.y + a2 * v1.y + a3 * tv.y + a4 * v2.y + a5 * v3.y + a6 * v4.y + a7 * v5.y;
      o.z = xv.z + bias + a1 * v0.z + a2 * v1.z + a3 * tv.z + a4 * v2.z + a5 * v3.z + a6 * v4.z + a7 * v5.z;
      o.w = xv.w + bias + a1 * v0.w + a2 * v1.w + a3 * tv.w + a4 * v2.w + a5 * v3.w + a6 * v4.w + a7 * v5.w;
      od[i] = o;
    }
  }
}

extern "C" void kernel_launch(void* const* d_in, const int* in_sizes, int n_in,
                              void* d_out, int out_size, void* d_ws, size_t ws_size,
                              hipStream_t stream) {
  const float* x      = (const float*)d_in[0];
  const float* ca_w1  = (const float*)d_in[1];
  const float* ca_w2  = (const float*)d_in[2];
  const float* s3_dw1 = (const float*)d_in[3];
  const float* s3_pw1 = (const float*)d_in[4];
  const float* s3_dw2 = (const float*)d_in[5];
  const float* s3_pw2 = (const float*)d_in[6];
  const float* s5_dw1 = (const float*)d_in[7];
  const float* s5_pw1 = (const float*)d_in[8];
  const float* s5_dw2 = (const float*)d_in[9];
  const float* s5_pw2 = (const float*)d_in[10];
  const float* d3_dw  = (const float*)d_in[11];
  const float* d3_pw  = (const float*)d_in[12];
  const float* d5_dw  = (const float*)d_in[13];
  const float* d5_pw  = (const float*)d_in[14];
  const float* at_w1  = (const float*)d_in[15];
  const float* at_w2  = (const float*)d_in[16];

  float* ws = (float*)d_ws;
  float* S = ws + OFF_S;  float* SQ = ws + OFF_SQ;  float* U = ws + OFF_U;
  float* mx = ws + OFF_MX; float* av = ws + OFF_AV; float* num = ws + OFF_NUM;
  float* ybuf = ws + OFF_Y; float* aco = ws + OFF_ACO; float* bia = ws + OFF_BIAS;
  int* ib = (int*)(ws + OFF_INT);
  int* idx = ib; int* selmap = ib + 16;
  float* R = ws + OFF_R;

  float* outf = (float*)d_out;
  float* scr = outf;             // 4 x IMG dw-stage scratch inside d_out (dead before k_final)
  float* t3  = outf + 4 * IMG;
  float* t5  = outf + 5 * IMG;
  float* out8 = outf + (size_t)B * C * HW;

  k_stats<<<B * C, 256, 0, stream>>>((const float4*)x, mx, av);
  k_se<<<B, 128, 0, stream>>>(mx, av, ca_w1, ca_w2, num);
  k_select<<<1, 256, 0, stream>>>(num, idx, selmap, ws);
  k_branchA<<<5 * 512, 256, 0, stream>>>(x, num, idx, d3_dw, d5_dw, s3_dw1, s5_dw1, R, scr, S, SQ);
  k_branchB<<<4 * 512, 256, 0, stream>>>(scr, d3_pw, d5_pw, s3_pw1, s5_pw1, R, t3, t5, S, SQ, U);
  k_branchC<<<2 * 512, 256, 0, stream>>>(t3, t5, s3_dw2, s5_dw2, scr, U);
  k_branchD<<<2 * 512, 256, 0, stream>>>(scr, s3_pw2, s5_pw2, R, S, SQ);
  k_att<<<B, 128, 0, stream>>>(S, SQ, at_w1, at_w2, ybuf, aco, bia);
  k_final<<<B * C + 1, 256, 0, stream>>>(x, num, selmap, idx, R, aco, bia, ybuf, outf, out8);
}